// Round 16
// baseline (77.026 us; speedup 1.0000x reference)
//
#include <hip/hip_runtime.h>
#include <hip/hip_bf16.h>

typedef __attribute__((ext_vector_type(8))) short short8_t;
typedef __attribute__((ext_vector_type(4))) float f32x4;

#define BATCH 16
#define CIN   512
#define COUT  512
#define TT    4096
#define BKT   32
#define NKT   16     // CIN / BKT

// pack 2 f32 -> u32 of 2 bf16 (RNE); pairs into v_cvt_pk_bf16_f32
__device__ __forceinline__ uint pk2(float a, float b) {
    ushort lo = __builtin_bit_cast(ushort, __float2bfloat16(a));
    ushort hi = __builtin_bit_cast(ushort, __float2bfloat16(b));
    return (uint)lo | ((uint)hi << 16);
}

#define SCHEDB()    __builtin_amdgcn_sched_barrier(0)
#define WAIT_VM0()  do { asm volatile("s_waitcnt vmcnt(0)" ::: "memory"); SCHEDB(); } while (0)
#define WAIT_VM4()  do { asm volatile("s_waitcnt vmcnt(4)" ::: "memory"); SCHEDB(); } while (0)
#define WAIT_VM6()  do { asm volatile("s_waitcnt vmcnt(6)" ::: "memory"); SCHEDB(); } while (0)
#define WAIT_LGKM() do { asm volatile("s_waitcnt lgkmcnt(0)" ::: "memory"); SCHEDB(); } while (0)
#define RAW_BARRIER() do { __builtin_amdgcn_s_barrier(); SCHEDB(); } while (0)

// ---------------------------------------------------------------------------
// Pre-pass: W (fp32 [512][512]) -> bf16 MFMA A-fragment order (verified R5-R15):
//   Wb[bm][ksg][g][r][8k], bm=m>>4, r=m&15, ksg=k>>5, g=(k>>3)&3
// ---------------------------------------------------------------------------
extern "C" __global__ __launch_bounds__(256)
void wconv(const float* __restrict__ W, ushort* __restrict__ Wb)
{
    const int i  = blockIdx.x * 256 + threadIdx.x;   // [0, 65536)
    const int m  = i >> 7;
    const int k0 = (i & 127) * 4;
    const float4 v = *(const float4*)(W + (size_t)m * CIN + k0);
    const int bm = m >> 4, r = m & 15;
    const int ksg = k0 >> 5, g = (k0 >> 3) & 3, k7 = k0 & 7;
    uint2 q;
    q.x = pk2(v.x, v.y);
    q.y = pk2(v.z, v.w);
    *(uint2*)&Wb[(size_t)bm * 8192 + ksg * 512 + g * 128 + r * 8 + k7] = q;
}

// ---------------------------------------------------------------------------
// Fused GEMM (R11 schedule, 2x wider block): tile 256m x 128t, BKT=32
// (16 steps), 512 threads = 8 waves as 4m x 2t (wave 64m x 64t, 16 MFMA/step).
// Per-thread vmcnt FIFO identical to R11 (G=2 gload_lds + A=4 per iter ->
// steady vmcnt(6) retires {A(kt), G(kt+1)}, keeps {A(kt+1), G(kt+2)} in
// flight across the raw barrier). All LDS patterns carried from R10-R15
// (measured 0-conflict): RAW linear [32k][128t] fp32; CVT b32 col reads
// (2-way free) + b128 wave-contiguous granule writes; frag reads 16-lane
// contiguous 256B. LDS: RAW 3x16K + BF 2x8K = 64 KiB -> 2 blocks/CU
// (16 waves/CU), A L2 traffic halved vs R11.
// ---------------------------------------------------------------------------
template<bool WSB>
__global__ __launch_bounds__(512)
void conv2x1_gemm(const float* __restrict__ pre, const float* __restrict__ W,
                  const ushort* __restrict__ Wb,
                  const float* __restrict__ bias, float* __restrict__ out)
{
    __shared__ float  RAW[3][BKT * 128];      // 3 x 16 KiB fp32 ring
    __shared__ ushort BF [2][4 * 128 * 8];    // 2 x 8 KiB bf16 granules [p][t][8k]

    const int tid  = threadIdx.x;
    const int lane = tid & 63;
    const int wv   = tid >> 6;          // [0,8)
    const int wm   = wv >> 1;           // [0,4): 64m strip
    const int wt   = wv & 1;            // [0,2): 64t strip
    const int g    = lane >> 4;
    const int l15  = lane & 15;

    // XCD-chunked bijective swizzle (1024 = 8*128); id pairs share a B-panel
    // (same bb, ti) on one XCD's L2.
    const int id   = ((blockIdx.x & 7) << 7) | (blockIdx.x >> 3);
    const int mblk = id & 1;
    const int ti   = (id >> 1) & 31;
    const int bb   = id >> 6;

    const int m0 = mblk << 8;   // {0, 256}
    const int t0 = ti << 7;     // [0,4096) step 128

    const float* preB   = pre + (size_t)bb * ((size_t)CIN * TT);
    const int    bmBase = (m0 >> 4) + wm * 4;

    f32x4 acc[4][4];
#pragma unroll
    for (int i = 0; i < 4; ++i)
#pragma unroll
        for (int j = 0; j < 4; ++j) acc[i][j] = (f32x4)0.0f;

    short8_t afA[4], afB[4];
    float    f[8];   // CVT staging (read early, write late)

    const int ct = tid & 127;   // CVT column
    const int cp = tid >> 7;    // CVT k-octet [0,4)

    // ---- B stage: 2 gload_lds (16B) per thread; RAW[J%3] linear [32k][128t] ----
#define STAGE(J) do { \
    _Pragma("unroll") \
    for (int i = 0; i < 2; ++i) { \
        const int s  = i*512 + tid;          /* [0,1024) 16B slots */ \
        const int kr = s >> 5;               /* [0,32) */ \
        const int tc = (s & 31) << 2;        /* [0,128) step 4 */ \
        const float* gsrc = preB + (size_t)((J)*BKT + kr) * TT + t0 + tc; \
        float* ldst = &RAW[(J) % 3][kr*128 + tc]; \
        __builtin_amdgcn_global_load_lds((const __attribute__((address_space(1))) void*)gsrc, \
                                         (__attribute__((address_space(3))) void*)ldst, 16, 0, 0); \
    } } while (0)

    // ---- A fragments for step KT (one ksg per step since BKT=32) ----
#define LOAD_A(KT, AF) do { \
    if constexpr (WSB) { \
        _Pragma("unroll") \
        for (int mi = 0; mi < 4; ++mi) \
            AF[mi] = *(const short8_t*)(Wb + (size_t)(bmBase + mi) * 8192 \
                                        + (KT) * 512 + g * 128 + l15 * 8); \
    } else { \
        _Pragma("unroll") \
        for (int mi = 0; mi < 4; ++mi) { \
            const float* ab = W + (size_t)(m0 + wm*64 + mi*16 + l15) * CIN + (KT)*BKT + g*8; \
            const float4 u0 = *(const float4*)ab; \
            const float4 u1 = *(const float4*)(ab + 4); \
            uint4 qq; \
            qq.x = pk2(u0.x, u0.y); qq.y = pk2(u0.z, u0.w); \
            qq.z = pk2(u1.x, u1.y); qq.w = pk2(u1.z, u1.w); \
            AF[mi] = __builtin_bit_cast(short8_t, qq); \
        } \
    } } while (0)

    // ---- CVT read: 8 b32 column reads (2-way bank, measured-free R10-15) ----
#define CVT_READ(J) do { \
    _Pragma("unroll") \
    for (int j = 0; j < 8; ++j) \
        f[j] = RAW[(J) % 3][(cp*8 + j) * 128 + ct]; \
    } while (0)

    // ---- CVT write: 1 b128 granule write (wave-contiguous 1KB, 0-conflict) ----
#define CVT_WRITE(J) do { \
    uint4 q; \
    q.x = pk2(f[0], f[1]); \
    q.y = pk2(f[2], f[3]); \
    q.z = pk2(f[4], f[5]); \
    q.w = pk2(f[6], f[7]); \
    *(uint4*)&BF[(J) & 1][cp * 1024 + ct * 8] = q; \
    } while (0)

    // ---- MFMA step: 4 b128 frag reads (16-lane contiguous ✓) + 16 MFMA ----
#define MFMA_STEP(J, AF) do { \
    __builtin_amdgcn_s_setprio(1); \
    short8_t bf[4]; \
    _Pragma("unroll") \
    for (int ni = 0; ni < 4; ++ni) \
        bf[ni] = *(const short8_t*)&BF[(J) & 1][g * 1024 + (wt*64 + ni*16 + l15) * 8]; \
    _Pragma("unroll") \
    for (int mi = 0; mi < 4; ++mi) \
        _Pragma("unroll") \
        for (int ni = 0; ni < 4; ++ni) \
            acc[mi][ni] = __builtin_amdgcn_mfma_f32_16x16x32_bf16(AF[mi], bf[ni], acc[mi][ni], 0, 0, 0); \
    __builtin_amdgcn_s_setprio(0); \
    } while (0)

    // -------- prologue: FIFO = [G0:2, G1:2, A0:4] --------
    STAGE(0);
    STAGE(1);
    LOAD_A(0, afA);
    WAIT_VM6();               // retire G(0); leave {G1, A0} in flight
    RAW_BARRIER();
    CVT_READ(0);
    CVT_WRITE(0);             // RAW[0] -> BF[0]

    // -------- main loop (R11 schedule, per-thread FIFO identical) --------
    // steady FIFO before wait: G(kt+1):2, A(kt):4 | A(kt+1):4, G(kt+2):2
#pragma unroll
    for (int kt = 0; kt < NKT; ++kt) {
        if (kt + 1 < NKT) {
            if ((kt & 1) == 0) LOAD_A(kt + 1, afB);
            else               LOAD_A(kt + 1, afA);
        }
        if (kt + 2 < NKT) STAGE(kt + 2);
        if      (kt + 2 < NKT) WAIT_VM6();   // retire {A(kt), G(kt+1)}
        else if (kt + 1 < NKT) WAIT_VM4();   // kt=14: no G(16) issued
        else                   WAIT_VM0();   // kt=15: drain
        WAIT_LGKM();                         // CVT writes / frag reads retired
        RAW_BARRIER();                       // BF[kt&1] + RAW[(kt+1)%3] visible
        if (kt + 1 < NKT) CVT_READ(kt + 1);  // issue early: latency under MFMA
        if ((kt & 1) == 0) MFMA_STEP(kt, afA);
        else               MFMA_STEP(kt, afB);
        if (kt + 1 < NKT) CVT_WRITE(kt + 1);
    }

    // -------- epilogue: out = 2*(acc + bias) --------
    const int orow = m0 + wm*64 + g*4;     // + mi*16 + r
    float bv[4][4];
#pragma unroll
    for (int mi = 0; mi < 4; ++mi)
#pragma unroll
        for (int r = 0; r < 4; ++r)
            bv[mi][r] = bias[orow + mi*16 + r];

    float* outB = out + (size_t)bb * ((size_t)COUT * TT);
#pragma unroll
    for (int mi = 0; mi < 4; ++mi) {
#pragma unroll
        for (int ni = 0; ni < 4; ++ni) {
            const int t = t0 + wt*64 + ni*16 + l15;
#pragma unroll
            for (int r = 0; r < 4; ++r) {
                const int o = orow + mi*16 + r;
                outB[(size_t)o * TT + t] = 2.0f * (acc[mi][ni][r] + bv[mi][r]);
            }
        }
    }
}

extern "C" void kernel_launch(void* const* d_in, const int* in_sizes, int n_in,
                              void* d_out, int out_size, void* d_ws, size_t ws_size,
                              hipStream_t stream)
{
    const float* pre  = (const float*)d_in[0];   // [16, 512, 4096] fp32
    const float* Wp   = (const float*)d_in[1];   // [512, 512] fp32
    const float* bias = (const float*)d_in[2];   // [512] fp32
    float* out = (float*)d_out;                  // [16, 512, 4096] fp32

    const size_t wb_bytes = (size_t)COUT * CIN * sizeof(ushort);   // 512 KiB

    const dim3 grid(BATCH * 2 * 32);   // 16 b x 2 m-tiles x 32 t-tiles = 1024
    const dim3 block(512);

    if (ws_size >= wb_bytes) {
        ushort* Wb = (ushort*)d_ws;
        hipLaunchKernelGGL(wconv, dim3(256), dim3(256), 0, stream, Wp, Wb);
        hipLaunchKernelGGL((conv2x1_gemm<true>), grid, block, 0, stream,
                           pre, Wp, Wb, bias, out);
    } else {
        hipLaunchKernelGGL((conv2x1_gemm<false>), grid, block, 0, stream,
                           pre, Wp, (const ushort*)nullptr, bias, out);
    }
}

// Round 17
// 73.573 us; speedup vs baseline: 1.0469x; 1.0469x over previous
//
#include <hip/hip_runtime.h>
#include <hip/hip_bf16.h>

typedef __attribute__((ext_vector_type(8))) short short8_t;
typedef __attribute__((ext_vector_type(4))) float f32x4;

#define BATCH 16
#define CIN   512
#define COUT  512
#define TT    4096
#define BKT   32
#define NKT   16     // CIN / BKT

// pack 2 f32 -> u32 of 2 bf16 (RNE); pairs into v_cvt_pk_bf16_f32
__device__ __forceinline__ uint pk2(float a, float b) {
    ushort lo = __builtin_bit_cast(ushort, __float2bfloat16(a));
    ushort hi = __builtin_bit_cast(ushort, __float2bfloat16(b));
    return (uint)lo | ((uint)hi << 16);
}

#define SCHEDB()    __builtin_amdgcn_sched_barrier(0)
#define WAIT_VM0()  do { asm volatile("s_waitcnt vmcnt(0)" ::: "memory"); SCHEDB(); } while (0)
#define WAIT_VM4()  do { asm volatile("s_waitcnt vmcnt(4)" ::: "memory"); SCHEDB(); } while (0)
#define WAIT_VM6()  do { asm volatile("s_waitcnt vmcnt(6)" ::: "memory"); SCHEDB(); } while (0)
#define WAIT_LGKM() do { asm volatile("s_waitcnt lgkmcnt(0)" ::: "memory"); SCHEDB(); } while (0)
#define RAW_BARRIER() do { __builtin_amdgcn_s_barrier(); SCHEDB(); } while (0)

// ---------------------------------------------------------------------------
// Pre-pass: W (fp32 [512][512]) -> bf16 MFMA A-fragment order (verified R5-R16):
//   Wb[bm][ksg][g][r][8k], bm=m>>4, r=m&15, ksg=k>>5, g=(k>>3)&3
// ---------------------------------------------------------------------------
extern "C" __global__ __launch_bounds__(256)
void wconv(const float* __restrict__ W, ushort* __restrict__ Wb)
{
    const int i  = blockIdx.x * 256 + threadIdx.x;   // [0, 65536)
    const int m  = i >> 7;
    const int k0 = (i & 127) * 4;
    const float4 v = *(const float4*)(W + (size_t)m * CIN + k0);
    const int bm = m >> 4, r = m & 15;
    const int ksg = k0 >> 5, g = (k0 >> 3) & 3, k7 = k0 & 7;
    uint2 q;
    q.x = pk2(v.x, v.y);
    q.y = pk2(v.z, v.w);
    *(uint2*)&Wb[(size_t)bm * 8192 + ksg * 512 + g * 128 + r * 8 + k7] = q;
}

// ---------------------------------------------------------------------------
// Fused GEMM == R11 (best, 72us) with exactly two deltas:
//   (1) RAW ring 3 -> 2 slots: LDS 32 KiB -> 24 KiB (static cap 6 blocks/CU).
//       Race-free: STAGE(kt+2) writes RAW[kt%2], which CVT(kt) finished
//       reading before the step-kt barrier (its ds reads drained by the
//       wave's lgkmcnt(0) before s_barrier).
//   (2) no s_setprio (m190: hurts lockstep GEMM; R11 didn't have it).
// Everything else byte-identical to R11: tile 256m x 64t, BKT=32, 4 waves,
// A 2-deep from L2-hot Wb, CVT one tile ahead, counted vmcnt(6)/4/0 + raw
// s_barrier, all LDS patterns measured 0-conflict.
// ---------------------------------------------------------------------------
template<bool WSB>
__global__ __launch_bounds__(256)
void conv2x1_gemm(const float* __restrict__ pre, const float* __restrict__ W,
                  const ushort* __restrict__ Wb,
                  const float* __restrict__ bias, float* __restrict__ out)
{
    __shared__ float  RAW[2][BKT * 64];      // 2 x 8 KiB fp32 ring
    __shared__ ushort BF [2][4 * 64 * 8];    // 2 x 4 KiB bf16 granules [p][t][8k]

    const int tid  = threadIdx.x;
    const int lane = tid & 63;
    const int wv   = tid >> 6;          // wave = 64m strip [0,4); cvt k-octet
    const int g    = lane >> 4;
    const int l15  = lane & 15;

    // XCD-chunked bijective swizzle (2048 = 8*256); consecutive ids share a
    // B-panel (same bb, ti) on one XCD's L2.
    const int id   = ((blockIdx.x & 7) << 8) | (blockIdx.x >> 3);
    const int mblk = id & 1;
    const int ti   = (id >> 1) & 63;
    const int bb   = id >> 7;

    const int m0 = mblk << 8;   // {0, 256}
    const int t0 = ti << 6;     // [0,4096) step 64

    const float* preB   = pre + (size_t)bb * ((size_t)CIN * TT);
    const int    bmBase = (m0 >> 4) + wv * 4;

    f32x4 acc[4][4];
#pragma unroll
    for (int i = 0; i < 4; ++i)
#pragma unroll
        for (int j = 0; j < 4; ++j) acc[i][j] = (f32x4)0.0f;

    short8_t afA[4], afB[4];
    float    f[8];   // CVT staging (read early, write late)

    // ---- B stage: 2 gload_lds (16B) per thread; RAW[J%2] linear [32k][64t] ----
#define STAGE(J) do { \
    _Pragma("unroll") \
    for (int i = 0; i < 2; ++i) { \
        const int krow = wv*8 + i*4 + (lane >> 4); \
        const float* gsrc = preB + (size_t)((J)*BKT + krow) * TT + t0 + ((lane & 15) << 2); \
        float* ldst = &RAW[(J) % 2][(wv*128 + i*64 + lane) * 4]; \
        __builtin_amdgcn_global_load_lds((const __attribute__((address_space(1))) void*)gsrc, \
                                         (__attribute__((address_space(3))) void*)ldst, 16, 0, 0); \
    } } while (0)

    // ---- A fragments for step KT (one ksg per step since BKT=32) ----
#define LOAD_A(KT, AF) do { \
    if constexpr (WSB) { \
        _Pragma("unroll") \
        for (int mi = 0; mi < 4; ++mi) \
            AF[mi] = *(const short8_t*)(Wb + (size_t)(bmBase + mi) * 8192 \
                                        + (KT) * 512 + g * 128 + l15 * 8); \
    } else { \
        _Pragma("unroll") \
        for (int mi = 0; mi < 4; ++mi) { \
            const float* ab = W + (size_t)(m0 + wv*64 + mi*16 + l15) * CIN + (KT)*BKT + g*8; \
            const float4 u0 = *(const float4*)ab; \
            const float4 u1 = *(const float4*)(ab + 4); \
            uint4 qq; \
            qq.x = pk2(u0.x, u0.y); qq.y = pk2(u0.z, u0.w); \
            qq.z = pk2(u1.x, u1.y); qq.w = pk2(u1.z, u1.w); \
            AF[mi] = __builtin_bit_cast(short8_t, qq); \
        } \
    } } while (0)

    // ---- CVT read: 8 b32 column reads (2-way bank, measured-free R10-16) ----
#define CVT_READ(J) do { \
    const int ct = tid & 63; \
    _Pragma("unroll") \
    for (int j = 0; j < 8; ++j) \
        f[j] = RAW[(J) % 2][(wv*8 + j) * 64 + ct]; \
    } while (0)

    // ---- CVT write: 1 b128 granule write (wave-contiguous 1KB, 0-conflict) ----
#define CVT_WRITE(J) do { \
    const int ct = tid & 63; \
    uint4 q; \
    q.x = pk2(f[0], f[1]); \
    q.y = pk2(f[2], f[3]); \
    q.z = pk2(f[4], f[5]); \
    q.w = pk2(f[6], f[7]); \
    *(uint4*)&BF[(J) & 1][wv * 512 + ct * 8] = q; \
    } while (0)

    // ---- MFMA step: 4 b128 frag reads (16-lane contiguous, 0-conflict) + 16 MFMA ----
#define MFMA_STEP(J, AF) do { \
    short8_t bf[4]; \
    _Pragma("unroll") \
    for (int ni = 0; ni < 4; ++ni) \
        bf[ni] = *(const short8_t*)&BF[(J) & 1][g * 512 + (ni*16 + l15) * 8]; \
    _Pragma("unroll") \
    for (int mi = 0; mi < 4; ++mi) \
        _Pragma("unroll") \
        for (int ni = 0; ni < 4; ++ni) \
            acc[mi][ni] = __builtin_amdgcn_mfma_f32_16x16x32_bf16(AF[mi], bf[ni], acc[mi][ni], 0, 0, 0); \
    } while (0)

    // -------- prologue: FIFO = [G0:2, G1:2, A0:4] --------
    STAGE(0);
    STAGE(1);
    LOAD_A(0, afA);
    WAIT_VM6();               // retire G(0); leave {G1, A0} in flight
    RAW_BARRIER();
    CVT_READ(0);
    CVT_WRITE(0);             // RAW[0] -> BF[0]

    // -------- main loop (R11 schedule, unchanged) --------
    // steady FIFO before wait: G(kt+1):2, A(kt):4 | A(kt+1):4, G(kt+2):2
#pragma unroll
    for (int kt = 0; kt < NKT; ++kt) {
        if (kt + 1 < NKT) {
            if ((kt & 1) == 0) LOAD_A(kt + 1, afB);
            else               LOAD_A(kt + 1, afA);
        }
        if (kt + 2 < NKT) STAGE(kt + 2);
        if      (kt + 2 < NKT) WAIT_VM6();   // retire {A(kt), G(kt+1)}
        else if (kt + 1 < NKT) WAIT_VM4();   // kt=14: no G(16) issued
        else                   WAIT_VM0();   // kt=15: drain
        WAIT_LGKM();                         // CVT writes / frag reads retired
        RAW_BARRIER();                       // BF[kt&1] + RAW[(kt+1)%2] visible
        if (kt + 1 < NKT) CVT_READ(kt + 1);  // issue early: latency under MFMA
        if ((kt & 1) == 0) MFMA_STEP(kt, afA);
        else               MFMA_STEP(kt, afB);
        if (kt + 1 < NKT) CVT_WRITE(kt + 1);
    }

    // -------- epilogue: out = 2*(acc + bias) --------
    const int orow = m0 + wv*64 + g*4;     // + mi*16 + r
    float bv[4][4];
#pragma unroll
    for (int mi = 0; mi < 4; ++mi)
#pragma unroll
        for (int r = 0; r < 4; ++r)
            bv[mi][r] = bias[orow + mi*16 + r];

    float* outB = out + (size_t)bb * ((size_t)COUT * TT);
#pragma unroll
    for (int mi = 0; mi < 4; ++mi) {
#pragma unroll
        for (int ni = 0; ni < 4; ++ni) {
            const int t = t0 + ni*16 + l15;
#pragma unroll
            for (int r = 0; r < 4; ++r) {
                const int o = orow + mi*16 + r;
                outB[(size_t)o * TT + t] = 2.0f * (acc[mi][ni][r] + bv[mi][r]);
            }
        }
    }
}

extern "C" void kernel_launch(void* const* d_in, const int* in_sizes, int n_in,
                              void* d_out, int out_size, void* d_ws, size_t ws_size,
                              hipStream_t stream)
{
    const float* pre  = (const float*)d_in[0];   // [16, 512, 4096] fp32
    const float* Wp   = (const float*)d_in[1];   // [512, 512] fp32
    const float* bias = (const float*)d_in[2];   // [512] fp32
    float* out = (float*)d_out;                  // [16, 512, 4096] fp32

    const size_t wb_bytes = (size_t)COUT * CIN * sizeof(ushort);   // 512 KiB

    const dim3 grid(BATCH * 2 * 64);   // 16 b x 2 m-tiles x 64 t-tiles = 2048
    const dim3 block(256);

    if (ws_size >= wb_bytes) {
        ushort* Wb = (ushort*)d_ws;
        hipLaunchKernelGGL(wconv, dim3(256), dim3(256), 0, stream, Wp, Wb);
        hipLaunchKernelGGL((conv2x1_gemm<true>), grid, block, 0, stream,
                           pre, Wp, Wb, bias, out);
    } else {
        hipLaunchKernelGGL((conv2x1_gemm<false>), grid, block, 0, stream,
                           pre, Wp, (const ushort*)nullptr, bias, out);
    }
}